// Round 1
// baseline (244.731 us; speedup 1.0000x reference)
//
#include <hip/hip_runtime.h>
#include <math.h>

#define B_    32
#define H_    512
#define W_    512
#define NBINS 256
#define NT    254
#define HW_   (H_ * W_)

// ws layout — every slot written unconditionally each replay. Cross-block
// communication uses the R2/R4-validated one-shot ticket pattern (atomicAdd +
// threadfence, agent-scope atomic loads on the reader side, NO spinning).
// Tickets are zeroed by a 132-B hipMemsetAsync each launch (ws is poisoned).
//   [0       .. 1048576)  int   hist_p[1024][256]   per-block Otsu-hist partial
//   [1048576 .. 2097152)  int   g0_p[1024][256]     per-block q-bucket count
//   [2097152 .. 3145728)  float g1_p[1024][256]     per-block q-bucket sum-p
//   [3145728 .. 3149824)  float p2_p[1024]          per-block sum p^2
//   [3149824 .. 3149952)  float totf[32]            per-batch mask count
//   [3149952 .. 3150080)  float lp[32]              per-batch loss
//   [3150080 .. 3150208)  int   bt[32]              per-batch arrival tickets
//   [3150208 .. 3150212)  int   gt                  global arrival ticket
#define OFF_G0   1048576
#define OFF_G1   2097152
#define OFF_P2   3145728
#define OFF_TOTF 3149824
#define OFF_LP   3149952
#define OFF_BT   3150080
#define OFF_GT   3150208
#define WS_NEED  3150212

__device__ __forceinline__ float max5(float a, float b, float c, float d, float e) {
    return fmaxf(fmaxf(fmaxf(a, b), fmaxf(c, d)), e);
}
__device__ __forceinline__ float4 fmax4(float4 a, float4 b) {
    return make_float4(fmaxf(a.x, b.x), fmaxf(a.y, b.y),
                       fmaxf(a.z, b.z), fmaxf(a.w, b.w));
}
__device__ __forceinline__ int bin_of(float im) {
    float v = im * 255.0f;                  // reference: v = imgs*255
    float u = v * (256.0f / 255.0f);        // reference: v*(NBINS/255.0) in f32
    int bin = (int)floorf(u);
    return bin < 0 ? 0 : (bin > NBINS - 1 ? NBINS - 1 : bin);
}

// Dilated-mask (5x5 max > 0) for 4 rows x 8 cols. Validated R7-R12.
__device__ __forceinline__ void dilate4(const float* __restrict__ lab,
                                        int rbase, int c0, int lane,
                                        unsigned mrow[4]) {
    float4 A[4], Bq[4];
#pragma unroll
    for (int r = 0; r < 4; ++r) {
        A[r]  = make_float4(0.f, 0.f, 0.f, 0.f);
        Bq[r] = A[r];
    }
#pragma unroll
    for (int k = 0; k < 8; ++k) {
        int gr = rbase - 2 + k;
        float4 la = make_float4(0.f, 0.f, 0.f, 0.f), lb = la;
        if ((unsigned)gr < (unsigned)H_) {
            la = *(const float4*)(lab + gr * W_ + c0);
            lb = *(const float4*)(lab + gr * W_ + c0 + 4);
        }
#pragma unroll
        for (int r = 0; r < 4; ++r)
            if (k >= r && k <= r + 4) { A[r] = fmax4(A[r], la); Bq[r] = fmax4(Bq[r], lb); }
    }
#pragma unroll
    for (int r = 0; r < 4; ++r) {
        float l2 = __shfl_up(Bq[r].z, 1);
        float l1 = __shfl_up(Bq[r].w, 1);
        float r1 = __shfl_down(A[r].x, 1);
        float r2 = __shfl_down(A[r].y, 1);
        if (lane == 0)  { l1 = 0.f; l2 = 0.f; }
        if (lane == 63) { r1 = 0.f; r2 = 0.f; }
        float e[12] = { l2, l1, A[r].x, A[r].y, A[r].z, A[r].w,
                        Bq[r].x, Bq[r].y, Bq[r].z, Bq[r].w, r1, r2 };
        unsigned m = 0;
#pragma unroll
        for (int c = 0; c < 8; ++c)
            if (max5(e[c], e[c+1], e[c+2], e[c+3], e[c+4]) > 0.f) m |= 1u << c;
        mrow[r] = m;
    }
}

// Per-pixel accumulate (validated R5-R12): Otsu hist + exact q-bucket + sum p^2.
__device__ __forceinline__ void px_acc(unsigned m, unsigned bit, float im, float p,
                                       int* s_hist, int* s_g0, float* s_g1,
                                       const float* s_thr, float& p2a) {
    if (m & bit) {
        atomicAdd(&s_hist[bin_of(im)], 1);
        int q0 = (int)(im * 255.0f);
        if (q0 > 254) q0 = 254;
        int q = q0;
        if (q0 < 254 && im >= s_thr[q0 + 1]) q = q0 + 1;
        else if (q0 > 0 && im < s_thr[q0])   q = q0 - 1;
        atomicAdd(&s_g0[q], 1);
        atomicAdd(&s_g1[q], p);
        p2a += p * p;
    }
}

// ---------------------------------------------------------------------------
// Fused kernel: dense single pass (R8/R12 main phase verbatim, 1024 blocks) +
// per-batch search/eval done by the 32nd-arriving band-block of each batch
// (one-shot ticket), + final mean by the 32nd-arriving batch (one-shot ticket).
// Search for batch b depends ONLY on batch b's 32 band partials, so no kernel
// boundary is needed — just the validated ticket/fence/agent-load pattern.
// ---------------------------------------------------------------------------
__global__ __launch_bounds__(256, 4) void k_all(const float* __restrict__ labels,
                                                const float* __restrict__ images,
                                                const float* __restrict__ preds,
                                                int* __restrict__ hist_p,
                                                int* __restrict__ g0_p,
                                                float* __restrict__ g1_p,
                                                float* __restrict__ p2_p,
                                                float* __restrict__ totf,
                                                float* __restrict__ lp,
                                                int* __restrict__ bt,
                                                int* __restrict__ gt,
                                                float* __restrict__ out) {
    __shared__ int   s_hist[NBINS];
    __shared__ int   s_g0[NBINS];
    __shared__ float s_g1[NBINS];
    __shared__ float s_thr[NBINS];
    __shared__ float s_red[256];
    // eval-phase extras (used only by the last-arriving block of each batch;
    // 13 KB total LDS -> still 4 blocks/CU)
    __shared__ float  sA[NBINS];
    __shared__ float  sB[NBINS];
    __shared__ double sD0[256];
    __shared__ double sD1[256];
    __shared__ unsigned long long s_pack[256];
    __shared__ double s_res[4];
    __shared__ int    s_last;

    const int tid   = threadIdx.x;
    const int lane  = tid & 63;
    const int w     = tid >> 6;
    const int band  = blockIdx.x;           // 0..31 (16-row bands)
    const int b     = blockIdx.y;           // 0..31
    const int slot  = b * 32 + band;
    const int rbase = band * 16 + w * 4;
    const int c0    = lane * 8;
    const float* lab = labels + (size_t)b * HW_;
    const float* img = images + (size_t)b * HW_;
    const float* prd = preds  + (size_t)b * HW_;

    s_hist[tid] = 0;
    s_g0[tid]   = 0;
    s_g1[tid]   = 0.0f;
    s_thr[tid]  = (float)tid / 255.0f;
    __syncthreads();

    unsigned mrow[4];
    dilate4(lab, rbase, c0, lane, mrow);

    float p2a = 0.0f;
#pragma unroll
    for (int r = 0; r < 4; ++r) {
        unsigned m = mrow[r];
        size_t off = (size_t)(rbase + r) * W_ + c0;
        // dense unconditional loads (sparse-load MLP collapse measured R4)
        float4 iv0 = *(const float4*)(img + off);
        float4 iv1 = *(const float4*)(img + off + 4);
        float4 pv0 = *(const float4*)(prd + off);
        float4 pv1 = *(const float4*)(prd + off + 4);
        px_acc(m,   1u, iv0.x, pv0.x, s_hist, s_g0, s_g1, s_thr, p2a);
        px_acc(m,   2u, iv0.y, pv0.y, s_hist, s_g0, s_g1, s_thr, p2a);
        px_acc(m,   4u, iv0.z, pv0.z, s_hist, s_g0, s_g1, s_thr, p2a);
        px_acc(m,   8u, iv0.w, pv0.w, s_hist, s_g0, s_g1, s_thr, p2a);
        px_acc(m,  16u, iv1.x, pv1.x, s_hist, s_g0, s_g1, s_thr, p2a);
        px_acc(m,  32u, iv1.y, pv1.y, s_hist, s_g0, s_g1, s_thr, p2a);
        px_acc(m,  64u, iv1.z, pv1.z, s_hist, s_g0, s_g1, s_thr, p2a);
        px_acc(m, 128u, iv1.w, pv1.w, s_hist, s_g0, s_g1, s_thr, p2a);
    }

    s_red[tid] = p2a;
    __syncthreads();
    // plain stores to this block's own slot (every slot written -> poison-safe)
    hist_p[(slot << 8) + tid] = s_hist[tid];
    g0_p  [(slot << 8) + tid] = s_g0[tid];
    g1_p  [(slot << 8) + tid] = s_g1[tid];
    for (int off = 128; off > 0; off >>= 1) {
        if (tid < off) s_red[tid] += s_red[tid + off];
        __syncthreads();
    }
    if (tid == 0) p2_p[slot] = s_red[0];

    // ---- per-batch arrival ticket (one-shot, no spin) --------------------
    // __syncthreads drains all threads' global stores (vmcnt(0) before
    // s_barrier); tid0's fence publishes them agent-wide before the ticket.
    __syncthreads();
    if (tid == 0) {
        __threadfence();
        int t = atomicAdd(&bt[b], 1);
        s_last = (t == 31) ? 1 : 0;
    }
    __syncthreads();
    if (!s_last) return;
    __threadfence();    // acquire side; reads below use agent-scope loads

    // ======================================================================
    // Eval phase: only the last-arriving block of batch b (256 threads).
    // Math verbatim from validated k_search_s / k_eval; partials read with
    // agent-scope atomic loads (sc1 -> coherent past this XCD's L2).
    // ======================================================================
    const float s = 1e-8f;

    // reduce 32 band-partials -> this batch's histogram bin `tid` (exact ints)
    int h = 0;
    {
        const int* hp = hist_p + ((b * 32) << 8) + tid;
#pragma unroll 8
        for (int j = 0; j < 32; ++j)
            h += __hip_atomic_load(hp + (j << 8), __ATOMIC_RELAXED,
                                   __HIP_MEMORY_SCOPE_AGENT);
    }
    s_g0[tid] = h;                           // reuse main-phase LDS as scratch
    __syncthreads();
    for (int off = 128; off > 0; off >>= 1) {
        if (tid < off) s_g0[tid] += s_g0[tid + off];
        __syncthreads();
    }
    const float ftot = (float)s_g0[0];
    __syncthreads();

    float pv = (float)h / ftot;
    s_g1[tid]  = pv;                         // p
    s_thr[tid] = pv * (float)tid;            // p*q
    __syncthreads();

    if (tid == 0) {                  // sequential fold == reference cumsum order
        float ch = 0.0f, cm = 0.0f;
#pragma unroll 8
        for (int i = 0; i < NBINS; ++i) {
            ch += s_g1[i];
            cm += s_thr[i];
            sA[i] = ch;
            sB[i] = cm;
        }
    }
    __syncthreads();

    const float tm = sB[NBINS - 1];
    unsigned long long best = 0ull;
    if (tid < NT) {
        const float cb  = sA[tid];
        const float m1v = sB[tid];
        const float w2  = 1.0f - cb;
        float mean2 = (tm - m1v) / (w2 + s);
        float d2 = mean2 - tm;
        const float t2v = w2 * (d2 * d2);
        for (int i = 0; i < NT; ++i) {
            float w0 = sA[i];
            float mean0 = sB[i] / (w0 + s);
            float d0 = mean0 - tm;
            float t0 = w0 * (d0 * d0);
            float w1 = cb - w0;
            float mean1 = (m1v - sB[i]) / (w1 + s);
            float d1 = mean1 - tm;
            float bv = (t0 + w1 * (d1 * d1)) + t2v;
            bool ok = (w0 > 0.f) && (w1 > 0.f) && (w2 > 0.f);
            bv = ok ? bv : 0.0f;
            unsigned k = (unsigned)(i * NT + tid);
            // bv >= 0: float-bit order == value order; ~k => first-max tie-break
            unsigned long long pk =
                ((unsigned long long)__float_as_uint(bv) << 32) | (0xFFFFFFFFu - k);
            best = pk > best ? pk : best;
        }
    }
    s_pack[tid] = best;
    __syncthreads();
    for (int off = 128; off > 0; off >>= 1) {
        if (tid < off) {
            unsigned long long o = s_pack[tid + off];
            if (o > s_pack[tid]) s_pack[tid] = o;
        }
        __syncthreads();
    }
    const int am = (int)(0xFFFFFFFFu - (unsigned)(s_pack[0] & 0xFFFFFFFFull));
    const int v  = am / NT + 1;             // im >= t1  <=>  q >= v
    const int wq = am % NT + 1;             // im >= t2  <=>  q >= wq

    // reduce g0/g1 partials for this batch (order matches validated k_eval)
    int   gc = 0;
    float gg = 0.0f;
    {
        const int*   gp  = g0_p + ((b * 32) << 8) + tid;
        const float* gfp = g1_p + ((b * 32) << 8) + tid;
#pragma unroll 8
        for (int j = 0; j < 32; ++j) {
            gc += __hip_atomic_load(gp  + (j << 8), __ATOMIC_RELAXED,
                                    __HIP_MEMORY_SCOPE_AGENT);
            gg += __hip_atomic_load(gfp + (j << 8), __ATOMIC_RELAXED,
                                    __HIP_MEMORY_SCOPE_AGENT);
        }
    }

    // f64 suffix sums S0/S1 at v and wq (validated R5-R12 math)
    sD0[tid] = (tid >= v) ? (double)gc : 0.0;
    sD1[tid] = (tid >= v) ? (double)gg : 0.0;
    __syncthreads();
    for (int off = 128; off > 0; off >>= 1) {
        if (tid < off) { sD0[tid] += sD0[tid + off]; sD1[tid] += sD1[tid + off]; }
        __syncthreads();
    }
    if (tid == 0) { s_res[0] = sD0[0]; s_res[1] = sD1[0]; }
    __syncthreads();

    sD0[tid] = (tid >= wq) ? (double)gc : 0.0;
    sD1[tid] = (tid >= wq) ? (double)gg : 0.0;
    __syncthreads();
    for (int off = 128; off > 0; off >>= 1) {
        if (tid < off) { sD0[tid] += sD0[tid + off]; sD1[tid] += sD1[tid + off]; }
        __syncthreads();
    }
    if (tid == 0) { s_res[2] = sD0[0]; s_res[3] = sD1[0]; }
    __syncthreads();

    // p2 partial reduce (32 values)
    sD0[tid] = (tid < 32)
        ? (double)__hip_atomic_load(p2_p + b * 32 + tid, __ATOMIC_RELAXED,
                                    __HIP_MEMORY_SCOPE_AGENT)
        : 0.0;
    __syncthreads();
    for (int off = 128; off > 0; off >>= 1) {
        if (tid < off) sD0[tid] += sD0[tid + off];
        __syncthreads();
    }

    if (tid == 0) {
        double S0v = s_res[0], S1v = s_res[1];
        double S0w = s_res[2], S1w = s_res[3];
        double c05 = (v <= wq) ? (S0v - S0w) : 0.0;
        double s05 = (v <= wq) ? (S1v - S1w) : 0.0;
        // sum (ci-p)^2 = |A| - 2*S1(A) + 0.25*|B\A| - S1(B\A) + sum p^2
        double sqd = S0w - 2.0 * S1w + 0.25 * c05 - s05 + sD0[0];
        float smv = ftot + 1e-8f;
        float lpv = (smv > 1e-8f) ? (float)sqd / smv : 0.0f;
        __hip_atomic_store(&lp[b], lpv, __ATOMIC_RELEASE, __HIP_MEMORY_SCOPE_AGENT);
        __hip_atomic_store(&totf[b], ftot, __ATOMIC_RELEASE, __HIP_MEMORY_SCOPE_AGENT);
        __threadfence();
        int t = atomicAdd(gt, 1);           // one-shot, no spin
        if (t == B_ - 1) {                  // last batch: all lp[]/totf[] published
            __threadfence();
            float sum = 0.0f;
            int   cnt = 0;
            for (int bb = 0; bb < B_; ++bb) {   // linear order == reference
                float tt = __hip_atomic_load(&totf[bb], __ATOMIC_RELAXED,
                                             __HIP_MEMORY_SCOPE_AGENT);
                float ll = __hip_atomic_load(&lp[bb], __ATOMIC_RELAXED,
                                             __HIP_MEMORY_SCOPE_AGENT);
                if (tt + 1e-8f > 1e-8f) { sum += ll; cnt += 1; }
            }
            out[0] = cnt > 0 ? sum / fmaxf((float)cnt, 1.0f) : 0.0f;
        }
    }
}

extern "C" void kernel_launch(void* const* d_in, const int* in_sizes, int n_in,
                              void* d_out, int out_size, void* d_ws, size_t ws_size,
                              hipStream_t stream) {
    const float* preds  = (const float*)d_in[0];
    const float* labels = (const float*)d_in[1];
    const float* images = (const float*)d_in[2];
    float* out = (float*)d_out;
    char* ws = (char*)d_ws;
    if (ws_size < (size_t)WS_NEED) return;  // harness ws is ~268 MB; never hit

    int*   hist_p = (int*)ws;
    int*   g0_p   = (int*)(ws + OFF_G0);
    float* g1_p   = (float*)(ws + OFF_G1);
    float* p2_p   = (float*)(ws + OFF_P2);
    float* totf   = (float*)(ws + OFF_TOTF);
    float* lp     = (float*)(ws + OFF_LP);
    int*   bt     = (int*)(ws + OFF_BT);
    int*   gt     = (int*)(ws + OFF_GT);

    // zero the 33 one-shot tickets (132 B) — ws arrives poisoned each replay;
    // hipMemsetAsync is graph-capture-safe (the harness itself enqueues it).
    hipMemsetAsync(ws + OFF_BT, 0, 132, stream);

    k_all<<<dim3(32, B_), 256, 0, stream>>>(labels, images, preds,
                                            hist_p, g0_p, g1_p, p2_p,
                                            totf, lp, bt, gt, out);
}

// Round 2
// 169.106 us; speedup vs baseline: 1.4472x; 1.4472x over previous
//
#include <hip/hip_runtime.h>
#include <math.h>

#define B_    32
#define H_    512
#define W_    512
#define NBINS 256
#define NT    254
#define HW_   (H_ * W_)

// ws layout — every slot written unconditionally each replay.
// Bulk kernel uses ONLY kernel-boundary coherence (R1 lesson: per-block
// __threadfence in the 1024-block kernel = ~1024 L2 writebacks = +120 µs).
// The one-shot ticket (fence + atomicAdd + agent loads, no spin) lives only
// in the 32-block tail, exactly as the validated R0 k_eval.
//   [0       .. 1048576)  int   hist_p[1024][256]   per-block Otsu-hist partial
//   [1048576 .. 2097152)  int   g0_p[1024][256]     per-block q-bucket count
//   [2097152 .. 3145728)  float g1_p[1024][256]     per-block q-bucket sum-p
//   [3145728 .. 3149824)  float p2_p[1024]          per-block sum p^2
//   [3149824 .. 3149952)  float totf[32]            per-batch mask count
//   [3149952 .. 3150080)  float lp[32]              per-batch loss
//   [3150080 .. 3150084)  int   gt                  global ticket (zeroed by k_main_p)
#define OFF_G0   1048576
#define OFF_G1   2097152
#define OFF_P2   3145728
#define OFF_TOTF 3149824
#define OFF_LP   3149952
#define OFF_GT   3150080
#define WS_NEED  3150084

__device__ __forceinline__ float max5(float a, float b, float c, float d, float e) {
    return fmaxf(fmaxf(fmaxf(a, b), fmaxf(c, d)), e);
}
__device__ __forceinline__ float4 fmax4(float4 a, float4 b) {
    return make_float4(fmaxf(a.x, b.x), fmaxf(a.y, b.y),
                       fmaxf(a.z, b.z), fmaxf(a.w, b.w));
}
__device__ __forceinline__ int bin_of(float im) {
    float v = im * 255.0f;                  // reference: v = imgs*255
    float u = v * (256.0f / 255.0f);        // reference: v*(NBINS/255.0) in f32
    int bin = (int)floorf(u);
    return bin < 0 ? 0 : (bin > NBINS - 1 ? NBINS - 1 : bin);
}

// Dilated-mask (5x5 max > 0) for 4 rows x 8 cols. Validated R7-R12.
__device__ __forceinline__ void dilate4(const float* __restrict__ lab,
                                        int rbase, int c0, int lane,
                                        unsigned mrow[4]) {
    float4 A[4], Bq[4];
#pragma unroll
    for (int r = 0; r < 4; ++r) {
        A[r]  = make_float4(0.f, 0.f, 0.f, 0.f);
        Bq[r] = A[r];
    }
#pragma unroll
    for (int k = 0; k < 8; ++k) {
        int gr = rbase - 2 + k;
        float4 la = make_float4(0.f, 0.f, 0.f, 0.f), lb = la;
        if ((unsigned)gr < (unsigned)H_) {
            la = *(const float4*)(lab + gr * W_ + c0);
            lb = *(const float4*)(lab + gr * W_ + c0 + 4);
        }
#pragma unroll
        for (int r = 0; r < 4; ++r)
            if (k >= r && k <= r + 4) { A[r] = fmax4(A[r], la); Bq[r] = fmax4(Bq[r], lb); }
    }
#pragma unroll
    for (int r = 0; r < 4; ++r) {
        float l2 = __shfl_up(Bq[r].z, 1);
        float l1 = __shfl_up(Bq[r].w, 1);
        float r1 = __shfl_down(A[r].x, 1);
        float r2 = __shfl_down(A[r].y, 1);
        if (lane == 0)  { l1 = 0.f; l2 = 0.f; }
        if (lane == 63) { r1 = 0.f; r2 = 0.f; }
        float e[12] = { l2, l1, A[r].x, A[r].y, A[r].z, A[r].w,
                        Bq[r].x, Bq[r].y, Bq[r].z, Bq[r].w, r1, r2 };
        unsigned m = 0;
#pragma unroll
        for (int c = 0; c < 8; ++c)
            if (max5(e[c], e[c+1], e[c+2], e[c+3], e[c+4]) > 0.f) m |= 1u << c;
        mrow[r] = m;
    }
}

// Per-pixel accumulate (validated R5-R12): Otsu hist + exact q-bucket + sum p^2.
__device__ __forceinline__ void px_acc(unsigned m, unsigned bit, float im, float p,
                                       int* s_hist, int* s_g0, float* s_g1,
                                       const float* s_thr, float& p2a) {
    if (m & bit) {
        atomicAdd(&s_hist[bin_of(im)], 1);
        int q0 = (int)(im * 255.0f);
        if (q0 > 254) q0 = 254;
        int q = q0;
        if (q0 < 254 && im >= s_thr[q0 + 1]) q = q0 + 1;
        else if (q0 > 0 && im < s_thr[q0])   q = q0 - 1;
        atomicAdd(&s_g0[q], 1);
        atomicAdd(&s_g1[q], p);
        p2a += p * p;
    }
}

// ---------------------------------------------------------------------------
// Kernel 1: dense single pass (R8/R12 best config, verbatim). 1024 blocks.
// No fences, no tickets here — kernel-boundary coherence only (R1 lesson).
// Also zeroes the tail kernel's ticket (plain store, boundary-ordered).
// ---------------------------------------------------------------------------
__global__ __launch_bounds__(256, 4) void k_main_p(const float* __restrict__ labels,
                                                   const float* __restrict__ images,
                                                   const float* __restrict__ preds,
                                                   int* __restrict__ hist_p,
                                                   int* __restrict__ g0_p,
                                                   float* __restrict__ g1_p,
                                                   float* __restrict__ p2_p,
                                                   int* __restrict__ gt) {
    __shared__ int   s_hist[NBINS];
    __shared__ int   s_g0[NBINS];
    __shared__ float s_g1[NBINS];
    __shared__ float s_thr[NBINS];
    __shared__ float s_red[256];

    const int tid   = threadIdx.x;
    const int lane  = tid & 63;
    const int w     = tid >> 6;
    const int band  = blockIdx.x;           // 0..31 (16-row bands)
    const int b     = blockIdx.y;           // 0..31
    const int slot  = b * 32 + band;
    const int rbase = band * 16 + w * 4;
    const int c0    = lane * 8;
    const float* lab = labels + (size_t)b * HW_;
    const float* img = images + (size_t)b * HW_;
    const float* prd = preds  + (size_t)b * HW_;

    if (band == 0 && b == 0 && tid == 0) *gt = 0;   // boundary-ordered reset

    s_hist[tid] = 0;
    s_g0[tid]   = 0;
    s_g1[tid]   = 0.0f;
    s_thr[tid]  = (float)tid / 255.0f;
    __syncthreads();

    unsigned mrow[4];
    dilate4(lab, rbase, c0, lane, mrow);

    float p2a = 0.0f;
#pragma unroll
    for (int r = 0; r < 4; ++r) {
        unsigned m = mrow[r];
        size_t off = (size_t)(rbase + r) * W_ + c0;
        // dense unconditional loads (sparse-load MLP collapse measured R4)
        float4 iv0 = *(const float4*)(img + off);
        float4 iv1 = *(const float4*)(img + off + 4);
        float4 pv0 = *(const float4*)(prd + off);
        float4 pv1 = *(const float4*)(prd + off + 4);
        px_acc(m,   1u, iv0.x, pv0.x, s_hist, s_g0, s_g1, s_thr, p2a);
        px_acc(m,   2u, iv0.y, pv0.y, s_hist, s_g0, s_g1, s_thr, p2a);
        px_acc(m,   4u, iv0.z, pv0.z, s_hist, s_g0, s_g1, s_thr, p2a);
        px_acc(m,   8u, iv0.w, pv0.w, s_hist, s_g0, s_g1, s_thr, p2a);
        px_acc(m,  16u, iv1.x, pv1.x, s_hist, s_g0, s_g1, s_thr, p2a);
        px_acc(m,  32u, iv1.y, pv1.y, s_hist, s_g0, s_g1, s_thr, p2a);
        px_acc(m,  64u, iv1.z, pv1.z, s_hist, s_g0, s_g1, s_thr, p2a);
        px_acc(m, 128u, iv1.w, pv1.w, s_hist, s_g0, s_g1, s_thr, p2a);
    }

    s_red[tid] = p2a;
    __syncthreads();
    // plain stores to this block's own slot (every slot written -> poison-safe)
    hist_p[(slot << 8) + tid] = s_hist[tid];
    g0_p  [(slot << 8) + tid] = s_g0[tid];
    g1_p  [(slot << 8) + tid] = s_g1[tid];
    for (int off = 128; off > 0; off >>= 1) {
        if (tid < off) s_red[tid] += s_red[tid + off];
        __syncthreads();
    }
    if (tid == 0) p2_p[slot] = s_red[0];
}

// ---------------------------------------------------------------------------
// Kernel 2: merged search + eval, 32 blocks (one per batch). Full 254x254
// Otsu argmax per block (math verbatim from R0 k_search_s / k_eval, both
// validated bit-exact), then loss + fused final mean via the R0-validated
// one-shot ticket (32 fences total — cheap; R1 proved 1024 are not).
// ---------------------------------------------------------------------------
__global__ __launch_bounds__(256) void k_tail(const int* __restrict__ hist_p,
                                              const int* __restrict__ g0_p,
                                              const float* __restrict__ g1_p,
                                              const float* __restrict__ p2_p,
                                              float* __restrict__ totf,
                                              float* __restrict__ lp,
                                              int* __restrict__ gt,
                                              float* __restrict__ out) {
    __shared__ float  sA[NBINS];
    __shared__ float  sB[NBINS];
    __shared__ float  sT0[NBINS];
    __shared__ float  sP[NBINS];
    __shared__ float  sQ[NBINS];
    __shared__ int    s_int[256];
    __shared__ unsigned long long s_pack[256];
    __shared__ double sD0[256];
    __shared__ double sD1[256];
    __shared__ double s_res[4];

    const int tid = threadIdx.x;
    const int b   = blockIdx.x;
    const float s = 1e-8f;

    // ---- histogram reduce: 32 band-partials -> bin `tid` (exact ints) ----
    int h = 0;
    {
        const int* hp = hist_p + ((b * 32) << 8) + tid;
#pragma unroll 8
        for (int j = 0; j < 32; ++j) h += hp[j << 8];
    }
    s_int[tid] = h;
    __syncthreads();
    for (int off = 128; off > 0; off >>= 1) {
        if (tid < off) s_int[tid] += s_int[tid + off];
        __syncthreads();
    }
    const float ftot = (float)s_int[0];
    __syncthreads();

    float pv = (float)h / ftot;
    sP[tid] = pv;
    sQ[tid] = pv * (float)tid;
    __syncthreads();

    if (tid == 0) {                  // sequential fold == reference cumsum order
        float ch = 0.0f, cm = 0.0f;
#pragma unroll 8
        for (int i = 0; i < NBINS; ++i) {
            ch += sP[i];
            cm += sQ[i];
            sA[i] = ch;
            sB[i] = cm;
        }
    }
    __syncthreads();

    const float tm = sB[NBINS - 1];
    if (tid < NT) {
        float w0 = sA[tid];
        float mean0 = sB[tid] / (w0 + s);
        float d0 = mean0 - tm;
        sT0[tid] = w0 * (d0 * d0);
    }
    __syncthreads();

    // ---- full 254x254 argmax: thread = column tid, loop rows i -----------
    unsigned long long best = 0ull;
    if (tid < NT) {
        const float cb  = sA[tid];
        const float m1v = sB[tid];
        const float w2  = 1.0f - cb;
        float mean2 = (tm - m1v) / (w2 + s);
        float d2 = mean2 - tm;
        const float t2v = w2 * (d2 * d2);
        for (int i = 0; i < NT; ++i) {
            float w0 = sA[i];
            float w1 = cb - w0;
            float mean1 = (m1v - sB[i]) / (w1 + s);
            float d1 = mean1 - tm;
            float bv = (sT0[i] + w1 * (d1 * d1)) + t2v;
            bool ok = (w0 > 0.f) && (w1 > 0.f) && (w2 > 0.f);
            bv = ok ? bv : 0.0f;
            unsigned k = (unsigned)(i * NT + tid);
            // bv >= 0: float-bit order == value order; ~k => first-max tie-break
            unsigned long long pk =
                ((unsigned long long)__float_as_uint(bv) << 32) | (0xFFFFFFFFu - k);
            best = pk > best ? pk : best;
        }
    }
    s_pack[tid] = best;
    __syncthreads();
    for (int off = 128; off > 0; off >>= 1) {
        if (tid < off) {
            unsigned long long o = s_pack[tid + off];
            if (o > s_pack[tid]) s_pack[tid] = o;
        }
        __syncthreads();
    }
    const int am = (int)(0xFFFFFFFFu - (unsigned)(s_pack[0] & 0xFFFFFFFFull));
    const int v  = am / NT + 1;             // im >= t1  <=>  q >= v
    const int wq = am % NT + 1;             // im >= t2  <=>  q >= wq

    // ---- reduce g0/g1 partials for this batch ----------------------------
    int   gc = 0;
    float gg = 0.0f;
    {
        const int*   gp  = g0_p + ((b * 32) << 8) + tid;
        const float* gfp = g1_p + ((b * 32) << 8) + tid;
#pragma unroll 8
        for (int j = 0; j < 32; ++j) { gc += gp[j << 8]; gg += gfp[j << 8]; }
    }

    // ---- f64 suffix sums S0/S1 at v and wq (validated R5-R12 math) -------
    sD0[tid] = (tid >= v) ? (double)gc : 0.0;
    sD1[tid] = (tid >= v) ? (double)gg : 0.0;
    __syncthreads();
    for (int off = 128; off > 0; off >>= 1) {
        if (tid < off) { sD0[tid] += sD0[tid + off]; sD1[tid] += sD1[tid + off]; }
        __syncthreads();
    }
    if (tid == 0) { s_res[0] = sD0[0]; s_res[1] = sD1[0]; }
    __syncthreads();

    sD0[tid] = (tid >= wq) ? (double)gc : 0.0;
    sD1[tid] = (tid >= wq) ? (double)gg : 0.0;
    __syncthreads();
    for (int off = 128; off > 0; off >>= 1) {
        if (tid < off) { sD0[tid] += sD0[tid + off]; sD1[tid] += sD1[tid + off]; }
        __syncthreads();
    }
    if (tid == 0) { s_res[2] = sD0[0]; s_res[3] = sD1[0]; }
    __syncthreads();

    // ---- p2 partial reduce (32 values) -----------------------------------
    sD0[tid] = (tid < 32) ? (double)p2_p[b * 32 + tid] : 0.0;
    __syncthreads();
    for (int off = 128; off > 0; off >>= 1) {
        if (tid < off) sD0[tid] += sD0[tid + off];
        __syncthreads();
    }

    if (tid == 0) {
        double S0v = s_res[0], S1v = s_res[1];
        double S0w = s_res[2], S1w = s_res[3];
        double c05 = (v <= wq) ? (S0v - S0w) : 0.0;
        double s05 = (v <= wq) ? (S1v - S1w) : 0.0;
        // sum (ci-p)^2 = |A| - 2*S1(A) + 0.25*|B\A| - S1(B\A) + sum p^2
        double sqd = S0w - 2.0 * S1w + 0.25 * c05 - s05 + sD0[0];
        float smv = ftot + 1e-8f;
        float lpv = (smv > 1e-8f) ? (float)sqd / smv : 0.0f;
        __hip_atomic_store(&lp[b], lpv, __ATOMIC_RELEASE, __HIP_MEMORY_SCOPE_AGENT);
        __hip_atomic_store(&totf[b], ftot, __ATOMIC_RELEASE, __HIP_MEMORY_SCOPE_AGENT);
        __threadfence();
        int t = atomicAdd(gt, 1);           // one-shot, no spin (R0-validated)
        if (t == B_ - 1) {                  // last block: all lp[]/totf[] published
            __threadfence();
            float sum = 0.0f;
            int   cnt = 0;
            for (int bb = 0; bb < B_; ++bb) {   // linear order == reference
                float tt = __hip_atomic_load(&totf[bb], __ATOMIC_RELAXED,
                                             __HIP_MEMORY_SCOPE_AGENT);
                float ll = __hip_atomic_load(&lp[bb], __ATOMIC_RELAXED,
                                             __HIP_MEMORY_SCOPE_AGENT);
                if (tt + 1e-8f > 1e-8f) { sum += ll; cnt += 1; }
            }
            out[0] = cnt > 0 ? sum / fmaxf((float)cnt, 1.0f) : 0.0f;
        }
    }
}

extern "C" void kernel_launch(void* const* d_in, const int* in_sizes, int n_in,
                              void* d_out, int out_size, void* d_ws, size_t ws_size,
                              hipStream_t stream) {
    const float* preds  = (const float*)d_in[0];
    const float* labels = (const float*)d_in[1];
    const float* images = (const float*)d_in[2];
    float* out = (float*)d_out;
    char* ws = (char*)d_ws;
    if (ws_size < (size_t)WS_NEED) return;  // harness ws is ~268 MB; never hit

    int*   hist_p = (int*)ws;
    int*   g0_p   = (int*)(ws + OFF_G0);
    float* g1_p   = (float*)(ws + OFF_G1);
    float* p2_p   = (float*)(ws + OFF_P2);
    float* totf   = (float*)(ws + OFF_TOTF);
    float* lp     = (float*)(ws + OFF_LP);
    int*   gt     = (int*)(ws + OFF_GT);

    k_main_p<<<dim3(32, B_), 256, 0, stream>>>(labels, images, preds,
                                               hist_p, g0_p, g1_p, p2_p, gt);
    k_tail<<<B_, 256, 0, stream>>>(hist_p, g0_p, g1_p, p2_p,
                                   totf, lp, gt, out);
}

// Round 3
// 147.510 us; speedup vs baseline: 1.6591x; 1.1464x over previous
//
#include <hip/hip_runtime.h>
#include <math.h>

#define B_    32
#define H_    512
#define W_    512
#define NBINS 256
#define NT    254
#define HW_   (H_ * W_)

// ws layout — every slot written unconditionally each replay.
// Bulk kernel uses ONLY kernel-boundary coherence (R1 lesson: per-block
// __threadfence in the 1024-block kernel = ~1024 L2 writebacks = +120 µs).
// The one-shot ticket (fence + atomicAdd + agent loads, no spin) lives only
// in the 32-block tail, exactly as the validated R0 k_eval.
//   [0       .. 1048576)  int   hist_p[1024][256]   per-block Otsu-hist partial
//   [1048576 .. 2097152)  int   g0_p[1024][256]     per-block q-bucket count
//   [2097152 .. 3145728)  float g1_p[1024][256]     per-block q-bucket sum-p
//   [3145728 .. 3149824)  float p2_p[1024]          per-block sum p^2
//   [3149824 .. 3149952)  float totf[32]            per-batch mask count
//   [3149952 .. 3150080)  float lp[32]              per-batch loss
//   [3150080 .. 3150084)  int   gt                  global ticket (zeroed by k_main_p)
#define OFF_G0   1048576
#define OFF_G1   2097152
#define OFF_P2   3145728
#define OFF_TOTF 3149824
#define OFF_LP   3149952
#define OFF_GT   3150080
#define WS_NEED  3150084

__device__ __forceinline__ float max5(float a, float b, float c, float d, float e) {
    return fmaxf(fmaxf(fmaxf(a, b), fmaxf(c, d)), e);
}
__device__ __forceinline__ float4 fmax4(float4 a, float4 b) {
    return make_float4(fmaxf(a.x, b.x), fmaxf(a.y, b.y),
                       fmaxf(a.z, b.z), fmaxf(a.w, b.w));
}
__device__ __forceinline__ int bin_of(float im) {
    float v = im * 255.0f;                  // reference: v = imgs*255
    float u = v * (256.0f / 255.0f);        // reference: v*(NBINS/255.0) in f32
    int bin = (int)floorf(u);
    return bin < 0 ? 0 : (bin > NBINS - 1 ? NBINS - 1 : bin);
}

// Dilated-mask (5x5 max > 0) for 4 rows x 8 cols. Validated R7-R12.
__device__ __forceinline__ void dilate4(const float* __restrict__ lab,
                                        int rbase, int c0, int lane,
                                        unsigned mrow[4]) {
    float4 A[4], Bq[4];
#pragma unroll
    for (int r = 0; r < 4; ++r) {
        A[r]  = make_float4(0.f, 0.f, 0.f, 0.f);
        Bq[r] = A[r];
    }
#pragma unroll
    for (int k = 0; k < 8; ++k) {
        int gr = rbase - 2 + k;
        float4 la = make_float4(0.f, 0.f, 0.f, 0.f), lb = la;
        if ((unsigned)gr < (unsigned)H_) {
            la = *(const float4*)(lab + gr * W_ + c0);
            lb = *(const float4*)(lab + gr * W_ + c0 + 4);
        }
#pragma unroll
        for (int r = 0; r < 4; ++r)
            if (k >= r && k <= r + 4) { A[r] = fmax4(A[r], la); Bq[r] = fmax4(Bq[r], lb); }
    }
#pragma unroll
    for (int r = 0; r < 4; ++r) {
        float l2 = __shfl_up(Bq[r].z, 1);
        float l1 = __shfl_up(Bq[r].w, 1);
        float r1 = __shfl_down(A[r].x, 1);
        float r2 = __shfl_down(A[r].y, 1);
        if (lane == 0)  { l1 = 0.f; l2 = 0.f; }
        if (lane == 63) { r1 = 0.f; r2 = 0.f; }
        float e[12] = { l2, l1, A[r].x, A[r].y, A[r].z, A[r].w,
                        Bq[r].x, Bq[r].y, Bq[r].z, Bq[r].w, r1, r2 };
        unsigned m = 0;
#pragma unroll
        for (int c = 0; c < 8; ++c)
            if (max5(e[c], e[c+1], e[c+2], e[c+3], e[c+4]) > 0.f) m |= 1u << c;
        mrow[r] = m;
    }
}

// Per-pixel accumulate (validated R5-R12): Otsu hist + exact q-bucket + sum p^2.
__device__ __forceinline__ void px_acc(unsigned m, unsigned bit, float im, float p,
                                       int* s_hist, int* s_g0, float* s_g1,
                                       const float* s_thr, float& p2a) {
    if (m & bit) {
        atomicAdd(&s_hist[bin_of(im)], 1);
        int q0 = (int)(im * 255.0f);
        if (q0 > 254) q0 = 254;
        int q = q0;
        if (q0 < 254 && im >= s_thr[q0 + 1]) q = q0 + 1;
        else if (q0 > 0 && im < s_thr[q0])   q = q0 - 1;
        atomicAdd(&s_g0[q], 1);
        atomicAdd(&s_g1[q], p);
        p2a += p * p;
    }
}

// ---------------------------------------------------------------------------
// Kernel 1: dense single pass (R8/R12 best config, verbatim). 1024 blocks.
// No fences, no tickets here — kernel-boundary coherence only (R1 lesson).
// Also zeroes the tail kernel's ticket (plain store, boundary-ordered).
// ---------------------------------------------------------------------------
__global__ __launch_bounds__(256, 4) void k_main_p(const float* __restrict__ labels,
                                                   const float* __restrict__ images,
                                                   const float* __restrict__ preds,
                                                   int* __restrict__ hist_p,
                                                   int* __restrict__ g0_p,
                                                   float* __restrict__ g1_p,
                                                   float* __restrict__ p2_p,
                                                   int* __restrict__ gt) {
    __shared__ int   s_hist[NBINS];
    __shared__ int   s_g0[NBINS];
    __shared__ float s_g1[NBINS];
    __shared__ float s_thr[NBINS];
    __shared__ float s_red[256];

    const int tid   = threadIdx.x;
    const int lane  = tid & 63;
    const int w     = tid >> 6;
    const int band  = blockIdx.x;           // 0..31 (16-row bands)
    const int b     = blockIdx.y;           // 0..31
    const int slot  = b * 32 + band;
    const int rbase = band * 16 + w * 4;
    const int c0    = lane * 8;
    const float* lab = labels + (size_t)b * HW_;
    const float* img = images + (size_t)b * HW_;
    const float* prd = preds  + (size_t)b * HW_;

    if (band == 0 && b == 0 && tid == 0) *gt = 0;   // boundary-ordered reset

    s_hist[tid] = 0;
    s_g0[tid]   = 0;
    s_g1[tid]   = 0.0f;
    s_thr[tid]  = (float)tid / 255.0f;
    __syncthreads();

    unsigned mrow[4];
    dilate4(lab, rbase, c0, lane, mrow);

    float p2a = 0.0f;
#pragma unroll
    for (int r = 0; r < 4; ++r) {
        unsigned m = mrow[r];
        size_t off = (size_t)(rbase + r) * W_ + c0;
        // dense unconditional loads (sparse-load MLP collapse measured R4)
        float4 iv0 = *(const float4*)(img + off);
        float4 iv1 = *(const float4*)(img + off + 4);
        float4 pv0 = *(const float4*)(prd + off);
        float4 pv1 = *(const float4*)(prd + off + 4);
        px_acc(m,   1u, iv0.x, pv0.x, s_hist, s_g0, s_g1, s_thr, p2a);
        px_acc(m,   2u, iv0.y, pv0.y, s_hist, s_g0, s_g1, s_thr, p2a);
        px_acc(m,   4u, iv0.z, pv0.z, s_hist, s_g0, s_g1, s_thr, p2a);
        px_acc(m,   8u, iv0.w, pv0.w, s_hist, s_g0, s_g1, s_thr, p2a);
        px_acc(m,  16u, iv1.x, pv1.x, s_hist, s_g0, s_g1, s_thr, p2a);
        px_acc(m,  32u, iv1.y, pv1.y, s_hist, s_g0, s_g1, s_thr, p2a);
        px_acc(m,  64u, iv1.z, pv1.z, s_hist, s_g0, s_g1, s_thr, p2a);
        px_acc(m, 128u, iv1.w, pv1.w, s_hist, s_g0, s_g1, s_thr, p2a);
    }

    s_red[tid] = p2a;
    __syncthreads();
    // plain stores to this block's own slot (every slot written -> poison-safe)
    hist_p[(slot << 8) + tid] = s_hist[tid];
    g0_p  [(slot << 8) + tid] = s_g0[tid];
    g1_p  [(slot << 8) + tid] = s_g1[tid];
    for (int off = 128; off > 0; off >>= 1) {
        if (tid < off) s_red[tid] += s_red[tid + off];
        __syncthreads();
    }
    if (tid == 0) p2_p[slot] = s_red[0];
}

// ---------------------------------------------------------------------------
// Kernel 2: merged search + eval, 32 blocks x 1024 threads (16 waves).
// R2 lesson: 256-thread tail was latency-bound at 52 µs — the 254-iter argmax
// loop dominated. Bit-safe reparallelizations only:
//   * hist band-reduce 4x wider (integer adds — order-free, exact)
//   * 254x254 argmax split over 4 row-groups (u64 max — order-free, exact)
// Every order-sensitive float/f64 phase (tid0 sequential cumsum, j=0..31
// sequential gg sum, 256-entry f64 suffix trees, final mean loop) is verbatim
// from the validated R0/R2 code, confined to tid<256.
// ---------------------------------------------------------------------------
__global__ __launch_bounds__(1024) void k_tail(const int* __restrict__ hist_p,
                                               const int* __restrict__ g0_p,
                                               const float* __restrict__ g1_p,
                                               const float* __restrict__ p2_p,
                                               float* __restrict__ totf,
                                               float* __restrict__ lp,
                                               int* __restrict__ gt,
                                               float* __restrict__ out) {
    __shared__ float  sA[NBINS];
    __shared__ float  sB[NBINS];
    __shared__ float  sT0[NBINS];
    __shared__ float  sT2[NBINS];
    __shared__ float  sP[NBINS];
    __shared__ float  sQ[NBINS];
    __shared__ int    s_int[1024];
    __shared__ unsigned long long s_pack[1024];
    __shared__ double sD0[256];
    __shared__ double sD1[256];
    __shared__ double s_res[4];

    const int tid = threadIdx.x;
    const int b   = blockIdx.x;
    const float s = 1e-8f;
    const int bin = tid & 255;          // 0..255
    const int grp = tid >> 8;           // 0..3

    // ---- histogram reduce: 32 band-partials -> bin, 4-way split (exact) --
    {
        const int* hp = hist_p + ((b * 32 + grp * 8) << 8) + bin;
        int hp8 = 0;
#pragma unroll
        for (int j = 0; j < 8; ++j) hp8 += hp[j << 8];
        s_int[tid] = hp8;
    }
    __syncthreads();
    int h = 0;
    if (tid < 256)
        h = s_int[tid] + s_int[tid + 256] + s_int[tid + 512] + s_int[tid + 768];
    __syncthreads();                    // all reads done before overwrite
    if (tid < 256) s_int[tid] = h;
    __syncthreads();
    for (int off = 128; off > 0; off >>= 1) {   // exact: integer counts
        if (tid < off) s_int[tid] += s_int[tid + off];
        __syncthreads();
    }
    const float ftot = (float)s_int[0];
    __syncthreads();

    if (tid < 256) {
        float pv = (float)h / ftot;
        sP[tid] = pv;
        sQ[tid] = pv * (float)tid;
    }
    __syncthreads();

    if (tid == 0) {                  // sequential fold == reference cumsum order
        float ch = 0.0f, cm = 0.0f;
#pragma unroll 8
        for (int i = 0; i < NBINS; ++i) {
            ch += sP[i];
            cm += sQ[i];
            sA[i] = ch;
            sB[i] = cm;
        }
    }
    __syncthreads();

    const float tm = sB[NBINS - 1];
    if (tid < NT) {
        float w0 = sA[tid];
        float mean0 = sB[tid] / (w0 + s);
        float d0 = mean0 - tm;
        sT0[tid] = w0 * (d0 * d0);
        float cb = sA[tid];
        float w2 = 1.0f - cb;
        float mean2 = (tm - sB[tid]) / (w2 + s);
        float d2 = mean2 - tm;
        sT2[tid] = w2 * (d2 * d2);
    }
    __syncthreads();

    // ---- 254x254 argmax: col = tid&255, rows split over 4 groups ---------
    // u64 max is order-independent -> bit-identical to the serial version.
    unsigned long long best = 0ull;
    if (bin < NT) {
        const float cb  = sA[bin];
        const float m1v = sB[bin];
        const float w2  = 1.0f - cb;
        const float t2v = sT2[bin];
        const int   i0  = grp * 64;
#pragma unroll 8
        for (int il = 0; il < 64; ++il) {
            int i = i0 + il;
            if (i >= NT) break;
            float w0 = sA[i];
            float w1 = cb - w0;
            float mean1 = (m1v - sB[i]) / (w1 + s);
            float d1 = mean1 - tm;
            float bv = (sT0[i] + w1 * (d1 * d1)) + t2v;
            bool ok = (w0 > 0.f) && (w1 > 0.f) && (w2 > 0.f);
            bv = ok ? bv : 0.0f;
            unsigned k = (unsigned)(i * NT + bin);
            // bv >= 0: float-bit order == value order; ~k => first-max tie-break
            unsigned long long pk =
                ((unsigned long long)__float_as_uint(bv) << 32) | (0xFFFFFFFFu - k);
            best = pk > best ? pk : best;
        }
    }
    s_pack[tid] = best;
    __syncthreads();
    for (int off = 512; off > 0; off >>= 1) {
        if (tid < off) {
            unsigned long long o = s_pack[tid + off];
            if (o > s_pack[tid]) s_pack[tid] = o;
        }
        __syncthreads();
    }
    const int am = (int)(0xFFFFFFFFu - (unsigned)(s_pack[0] & 0xFFFFFFFFull));
    const int v  = am / NT + 1;             // im >= t1  <=>  q >= v
    const int wq = am % NT + 1;             // im >= t2  <=>  q >= wq

    // ---- reduce g0/g1 partials (verbatim: j order preserved for gg) ------
    int   gc = 0;
    float gg = 0.0f;
    if (tid < 256) {
        const int*   gp  = g0_p + ((b * 32) << 8) + tid;
        const float* gfp = g1_p + ((b * 32) << 8) + tid;
#pragma unroll 8
        for (int j = 0; j < 32; ++j) { gc += gp[j << 8]; gg += gfp[j << 8]; }
    }

    // ---- f64 suffix sums S0/S1 at v and wq (validated, 256-tree verbatim) -
    if (tid < 256) {
        sD0[tid] = (tid >= v) ? (double)gc : 0.0;
        sD1[tid] = (tid >= v) ? (double)gg : 0.0;
    }
    __syncthreads();
    for (int off = 128; off > 0; off >>= 1) {
        if (tid < off) { sD0[tid] += sD0[tid + off]; sD1[tid] += sD1[tid + off]; }
        __syncthreads();
    }
    if (tid == 0) { s_res[0] = sD0[0]; s_res[1] = sD1[0]; }
    __syncthreads();

    if (tid < 256) {
        sD0[tid] = (tid >= wq) ? (double)gc : 0.0;
        sD1[tid] = (tid >= wq) ? (double)gg : 0.0;
    }
    __syncthreads();
    for (int off = 128; off > 0; off >>= 1) {
        if (tid < off) { sD0[tid] += sD0[tid + off]; sD1[tid] += sD1[tid + off]; }
        __syncthreads();
    }
    if (tid == 0) { s_res[2] = sD0[0]; s_res[3] = sD1[0]; }
    __syncthreads();

    // ---- p2 partial reduce (32 values, 256-tree verbatim) ----------------
    if (tid < 256)
        sD0[tid] = (tid < 32) ? (double)p2_p[b * 32 + tid] : 0.0;
    __syncthreads();
    for (int off = 128; off > 0; off >>= 1) {
        if (tid < off) sD0[tid] += sD0[tid + off];
        __syncthreads();
    }

    if (tid == 0) {
        double S0v = s_res[0], S1v = s_res[1];
        double S0w = s_res[2], S1w = s_res[3];
        double c05 = (v <= wq) ? (S0v - S0w) : 0.0;
        double s05 = (v <= wq) ? (S1v - S1w) : 0.0;
        // sum (ci-p)^2 = |A| - 2*S1(A) + 0.25*|B\A| - S1(B\A) + sum p^2
        double sqd = S0w - 2.0 * S1w + 0.25 * c05 - s05 + sD0[0];
        float smv = ftot + 1e-8f;
        float lpv = (smv > 1e-8f) ? (float)sqd / smv : 0.0f;
        __hip_atomic_store(&lp[b], lpv, __ATOMIC_RELEASE, __HIP_MEMORY_SCOPE_AGENT);
        __hip_atomic_store(&totf[b], ftot, __ATOMIC_RELEASE, __HIP_MEMORY_SCOPE_AGENT);
        __threadfence();
        int t = atomicAdd(gt, 1);           // one-shot, no spin (R0-validated)
        if (t == B_ - 1) {                  // last block: all lp[]/totf[] published
            __threadfence();
            float sum = 0.0f;
            int   cnt = 0;
            for (int bb = 0; bb < B_; ++bb) {   // linear order == reference
                float tt = __hip_atomic_load(&totf[bb], __ATOMIC_RELAXED,
                                             __HIP_MEMORY_SCOPE_AGENT);
                float ll = __hip_atomic_load(&lp[bb], __ATOMIC_RELAXED,
                                             __HIP_MEMORY_SCOPE_AGENT);
                if (tt + 1e-8f > 1e-8f) { sum += ll; cnt += 1; }
            }
            out[0] = cnt > 0 ? sum / fmaxf((float)cnt, 1.0f) : 0.0f;
        }
    }
}

extern "C" void kernel_launch(void* const* d_in, const int* in_sizes, int n_in,
                              void* d_out, int out_size, void* d_ws, size_t ws_size,
                              hipStream_t stream) {
    const float* preds  = (const float*)d_in[0];
    const float* labels = (const float*)d_in[1];
    const float* images = (const float*)d_in[2];
    float* out = (float*)d_out;
    char* ws = (char*)d_ws;
    if (ws_size < (size_t)WS_NEED) return;  // harness ws is ~268 MB; never hit

    int*   hist_p = (int*)ws;
    int*   g0_p   = (int*)(ws + OFF_G0);
    float* g1_p   = (float*)(ws + OFF_G1);
    float* p2_p   = (float*)(ws + OFF_P2);
    float* totf   = (float*)(ws + OFF_TOTF);
    float* lp     = (float*)(ws + OFF_LP);
    int*   gt     = (int*)(ws + OFF_GT);

    k_main_p<<<dim3(32, B_), 256, 0, stream>>>(labels, images, preds,
                                               hist_p, g0_p, g1_p, p2_p, gt);
    k_tail<<<B_, 1024, 0, stream>>>(hist_p, g0_p, g1_p, p2_p,
                                    totf, lp, gt, out);
}